// Round 14
// baseline (281.440 us; speedup 1.0000x reference)
//
#include <hip/hip_runtime.h>

// GraphSAGE 2-layer: CSR gather-mean (bf16) + bf16 MFMA fused GEMMs.
// R14: gathers are VMEM-instruction-bound (evidence: D=128 and D=256 gathers
//      both 60us despite 2x byte/VALU difference). Cut VMEM instructions:
//      (a) gather<128>: 4 rows per dwordx4 wave-load (16 lanes/row), edge id
//          via __shfl; (b) offs2 packed (beg,end) single 8B load per node.
//      GEMM + CSR identical to R13.

constexpr int NN   = 100000;
constexpr int NE   = 625000;
constexpr int DIN  = 128;
constexpr int DHID = 256;
constexpr int NB   = (NN + 255) / 256;          // 391 scan chunks
constexpr int CONV_BLKS = NN * DIN / 8 / 256;   // 6250 (exact)

using short8 = __attribute__((ext_vector_type(8))) short;
using f32x4  = __attribute__((ext_vector_type(4))) float;

__device__ __forceinline__ float bf2f(unsigned int u) {
    return __uint_as_float(u << 16);
}
__device__ __forceinline__ unsigned short f2b(float f) {
    unsigned int u = __float_as_uint(f);
    unsigned int r = (u + 0x7fffu + ((u >> 16) & 1u)) >> 16;   // RNE
    return (unsigned short)r;
}
__device__ __forceinline__ unsigned int pack2(float lo, float hi) {
    return (unsigned int)f2b(lo) | ((unsigned int)f2b(hi) << 16);
}
__device__ __forceinline__ void gload16(const void* g, void* lds) {
    __builtin_amdgcn_global_load_lds(
        (const __attribute__((address_space(1))) void*)g,
        (__attribute__((address_space(3))) void*)lds, 16, 0, 0);
}

// ---------------- CSR build ------------------------------------------------
__global__ __launch_bounds__(256) void hist_kernel(const int* __restrict__ dst,
                                                   int* __restrict__ hist)
{
    int t = blockIdx.x * 256 + threadIdx.x;
    if (t < NE) atomicAdd(&hist[dst[t]], 1);
}

__global__ __launch_bounds__(256) void chunk_sum_kernel(const int* __restrict__ hist,
                                                        int* __restrict__ bsum)
{
    __shared__ int s[256];
    int i = blockIdx.x * 256 + threadIdx.x;
    s[threadIdx.x] = (i < NN) ? hist[i] : 0;
    __syncthreads();
    for (int off = 128; off > 0; off >>= 1) {
        if (threadIdx.x < off) s[threadIdx.x] += s[threadIdx.x + off];
        __syncthreads();
    }
    if (threadIdx.x == 0) bsum[blockIdx.x] = s[0];
}

// per-chunk exclusive scan; each block redundantly computes its bsum-prefix.
// Writes offs2[i] = (beg, end) packed (one aligned 8B load at gather time).
__global__ __launch_bounds__(256) void scatter_offs_kernel(
    const int* __restrict__ hist, const int* __restrict__ bsum,
    int2* __restrict__ offs2, int* __restrict__ cursor)
{
    __shared__ int s[256];
    const int t = threadIdx.x;
    const int b = blockIdx.x;

    int acc = 0;
    for (int i = t; i < b; i += 256) acc += bsum[i];
    s[t] = acc;
    __syncthreads();
    for (int off = 128; off > 0; off >>= 1) {
        if (t < off) s[t] += s[t + off];
        __syncthreads();
    }
    const int bpre = s[0];
    __syncthreads();

    int i = b * 256 + t;
    int v = (i < NN) ? hist[i] : 0;
    s[t] = v;
    __syncthreads();
    for (int off = 1; off < 256; off <<= 1) {
        int u = (t >= off) ? s[t - off] : 0;
        __syncthreads();
        s[t] += u;
        __syncthreads();
    }
    int excl = s[t] - v + bpre;
    if (i < NN) {
        offs2[i]  = make_int2(excl, excl + v);
        cursor[i] = excl;
    }
}

__global__ __launch_bounds__(256) void perm_kernel(const int* __restrict__ src,
                                                   const int* __restrict__ dst,
                                                   int* __restrict__ cursor,
                                                   int* __restrict__ perm)
{
    int t = blockIdx.x * 256 + threadIdx.x;
    if (t < NE) {
        int p = atomicAdd(&cursor[dst[t]], 1);
        perm[p] = src[t];
    }
}

// ---------------- merged prep: x->bf16, WT0, WT1, zero hist ----------------
__global__ __launch_bounds__(256) void prep_all_kernel(
    const float* __restrict__ x, unsigned short* __restrict__ xb,
    const float* __restrict__ Wl0, const float* __restrict__ Wr0,
    unsigned short* __restrict__ WT0,
    const float* __restrict__ Wl1, const float* __restrict__ Wr1,
    unsigned short* __restrict__ WT1,
    int* __restrict__ hist)
{
    int b = blockIdx.x;
    if (b < CONV_BLKS) {
        int t = b * 256 + threadIdx.x;          // [0, 1.6M) exact
        float4 v0 = reinterpret_cast<const float4*>(x)[t * 2 + 0];
        float4 v1 = reinterpret_cast<const float4*>(x)[t * 2 + 1];
        uint4 o;
        o.x = pack2(v0.x, v0.y); o.y = pack2(v0.z, v0.w);
        o.z = pack2(v1.x, v1.y); o.w = pack2(v1.z, v1.w);
        reinterpret_cast<uint4*>(xb)[t] = o;
    } else if (b < CONV_BLKS + 256) {
        int t = (b - CONV_BLKS) * 256 + threadIdx.x;   // [0, 65536)
        int n = t >> 8, k = t & 255;
        float v = (k < DIN) ? Wl0[(size_t)k * DHID + n]
                            : Wr0[(size_t)(k - DIN) * DHID + n];
        WT0[t] = f2b(v);
    } else if (b < CONV_BLKS + 256 + 512) {
        int t = (b - CONV_BLKS - 256) * 256 + threadIdx.x;   // [0, 131072)
        int n = t >> 9, k = t & 511;
        float v = (k < DHID) ? Wl1[(size_t)k * DHID + n]
                             : Wr1[(size_t)(k - DHID) * DHID + n];
        WT1[t] = f2b(v);
    } else {
        int t = (b - CONV_BLKS - 256 - 512) * 256 + threadIdx.x;
        if (t < NN) hist[t] = 0;
    }
}

// ---------------- gather-mean, D=128: 4 rows per wave-load ------------------
// Lane l: quad q = l>>4 (edge 4g+q of group g), col-chunk c = l&15 (16B).
// One dwordx4 wave-load fetches 4 full 256B rows. Edge id via __shfl.
__global__ __launch_bounds__(256) void gather_mean128_kernel(
    const int2* __restrict__ offs2, const int* __restrict__ perm,
    const unsigned short* __restrict__ feat, unsigned short* __restrict__ agg)
{
    const int w = (blockIdx.x * 256 + threadIdx.x) >> 6;
    const int l = threadIdx.x & 63;
    const int q = l >> 4;
    const int c = l & 15;
    if (w >= NN) return;
    const int2 be = offs2[w];
    const int beg = be.x, deg = be.y - be.x;
    const float sc = 1.0f / (float)(deg > 1 ? deg : 1);

    const uint4* base = reinterpret_cast<const uint4*>(feat);   // 16/row
    float A0[8] = {}, A1[8] = {}, A2[8] = {}, A3[8] = {};
    for (int e0 = 0; e0 < deg; e0 += 64) {
        const int chunk = min(deg - e0, 64);
        int pv = (l < chunk) ? perm[beg + e0 + l] : 0;
        auto doquad = [&](float* A, int g) {        // edges 4g .. 4g+3
            int s   = __shfl(pv, 4 * g + q);
            float m = (4 * g + q < chunk) ? 1.0f : 0.0f;
            uint4 v = base[(size_t)s * 16 + c];
            A[0] = fmaf(bf2f(v.x & 0xffffu), m, A[0]);
            A[1] = fmaf(bf2f(v.x >> 16),     m, A[1]);
            A[2] = fmaf(bf2f(v.y & 0xffffu), m, A[2]);
            A[3] = fmaf(bf2f(v.y >> 16),     m, A[3]);
            A[4] = fmaf(bf2f(v.z & 0xffffu), m, A[4]);
            A[5] = fmaf(bf2f(v.z >> 16),     m, A[5]);
            A[6] = fmaf(bf2f(v.w & 0xffffu), m, A[6]);
            A[7] = fmaf(bf2f(v.w >> 16),     m, A[7]);
        };
        const int nq = (chunk + 3) >> 2;
        int g = 0;
        for (; g + 4 <= nq; g += 4) {
            doquad(A0, g); doquad(A1, g + 1);
            doquad(A2, g + 2); doquad(A3, g + 3);
        }
        if (g     < nq) doquad(A0, g);
        if (g + 1 < nq) doquad(A1, g + 1);
        if (g + 2 < nq) doquad(A2, g + 2);
    }
    float r[8];
    #pragma unroll
    for (int j = 0; j < 8; ++j) {
        r[j] = (A0[j] + A1[j]) + (A2[j] + A3[j]);
        r[j] += __shfl_xor(r[j], 16);
        r[j] += __shfl_xor(r[j], 32);
        r[j] *= sc;
    }
    if (l < 16) {
        uint4 o;
        o.x = pack2(r[0], r[1]); o.y = pack2(r[2], r[3]);
        o.z = pack2(r[4], r[5]); o.w = pack2(r[6], r[7]);
        reinterpret_cast<uint4*>(agg)[(size_t)w * 16 + c] = o;
    }
}

// ---------------- gather-mean, D=256: 2 rows per wave-load (pairs) ---------
__global__ __launch_bounds__(256) void gather_mean256_kernel(
    const int2* __restrict__ offs2, const int* __restrict__ perm,
    const unsigned short* __restrict__ feat, unsigned short* __restrict__ agg)
{
    const int w = (blockIdx.x * 256 + threadIdx.x) >> 6;
    const int l = threadIdx.x & 63;
    const int h = l >> 5;
    const int c = l & 31;
    if (w >= NN) return;
    const int2 be = offs2[w];
    const int beg = be.x, deg = be.y - be.x;
    const float sc = 1.0f / (float)(deg > 1 ? deg : 1);

    const uint4* base = reinterpret_cast<const uint4*>(feat);   // 32/row
    float A0[8] = {}, A1[8] = {}, A2[8] = {}, A3[8] = {};
    for (int e0 = 0; e0 < deg; e0 += 64) {
        const int chunk = min(deg - e0, 64);
        int pv = (l < chunk) ? perm[beg + e0 + l] : 0;
        auto dopair = [&](float* A, int p) {
            int sA = __builtin_amdgcn_readlane(pv, 2 * p);
            int sB = __builtin_amdgcn_readlane(pv, 2 * p + 1);
            int e  = 2 * p + h;
            int s  = h ? sB : sA;
            float m = (e < chunk) ? 1.0f : 0.0f;
            uint4 v = base[(size_t)s * 32 + c];
            A[0] = fmaf(bf2f(v.x & 0xffffu), m, A[0]);
            A[1] = fmaf(bf2f(v.x >> 16),     m, A[1]);
            A[2] = fmaf(bf2f(v.y & 0xffffu), m, A[2]);
            A[3] = fmaf(bf2f(v.y >> 16),     m, A[3]);
            A[4] = fmaf(bf2f(v.z & 0xffffu), m, A[4]);
            A[5] = fmaf(bf2f(v.z >> 16),     m, A[5]);
            A[6] = fmaf(bf2f(v.w & 0xffffu), m, A[6]);
            A[7] = fmaf(bf2f(v.w >> 16),     m, A[7]);
        };
        const int np = (chunk + 1) >> 1;
        int p = 0;
        for (; p + 4 <= np; p += 4) {
            dopair(A0, p); dopair(A1, p + 1);
            dopair(A2, p + 2); dopair(A3, p + 3);
        }
        if (p     < np) dopair(A0, p);
        if (p + 1 < np) dopair(A1, p + 1);
        if (p + 2 < np) dopair(A2, p + 2);
    }
    float r[8];
    #pragma unroll
    for (int j = 0; j < 8; ++j) {
        r[j] = (A0[j] + A1[j]) + (A2[j] + A3[j]);
        r[j] += __shfl_xor(r[j], 32);
        r[j] *= sc;
    }
    if (l < 32) {
        uint4 o;
        o.x = pack2(r[0], r[1]); o.y = pack2(r[2], r[3]);
        o.z = pack2(r[4], r[5]); o.w = pack2(r[6], r[7]);
        reinterpret_cast<uint4*>(agg)[(size_t)w * 32 + c] = o;
    }
}

// ---------------- bf16 MFMA fused SAGE GEMM (256x256, 16 waves, 2-buf) -----
template <int KP, bool WF, bool WB>
__global__ __launch_bounds__(1024) void sage_mfma_gemm(
    const unsigned short* __restrict__ Aagg,  // [M, KP] bf16
    const unsigned short* __restrict__ Axr,   // [M, KP] bf16
    const unsigned short* __restrict__ WT,    // [256, 2KP] bf16
    const float* __restrict__ bias,
    float* __restrict__ outf,                 // used if WF
    unsigned short* __restrict__ outb,        // used if WB
    int M)
{
    __shared__ __align__(16) unsigned short As[2 * 8192];   // 2 x [256][32]
    __shared__ __align__(16) unsigned short Bs[2 * 8192];   // 2 x [256][32]

    const int t   = threadIdx.x;
    const int l   = t & 63;
    const int wid = t >> 6;          // 0..15
    const int wr  = wid >> 2;        // 0..3
    const int wc  = wid & 3;         // 0..3
    const int m0  = blockIdx.x * 256;

    const int rin = l >> 2;                       // row within 16-row chunk
    const int csw = (l & 3) ^ ((l >> 3) & 3);     // swizzled source chunk

    const int sc0 = wid * 2, sc1 = sc0 + 1;

    constexpr int K2 = 2 * KP;
    constexpr int KT = K2 / 32;

    auto stageChunk = [&](int buf, int kt, int ch) {
        const int kb = kt * 32;
        if (ch < 16) {              // A chunk: rows m0+ch*16 .. +16
            const unsigned short* Asrc;
            int kk;
            if (kb < KP) { Asrc = Aagg; kk = kb; }
            else         { Asrc = Axr;  kk = kb - KP; }
            int row = m0 + ch * 16 + rin; if (row >= M) row = M - 1;
            gload16(Asrc + (size_t)row * KP + kk + csw * 8,
                    As + buf * 8192 + ch * 512);
        } else {                    // B chunk: WT rows (ch-16)*16 .. +16
            int row = (ch - 16) * 16 + rin;
            gload16(WT + (size_t)row * K2 + kb + csw * 8,
                    Bs + buf * 8192 + (ch - 16) * 512);
        }
    };
    auto stage = [&](int buf, int kt) {
        stageChunk(buf, kt, sc0);
        stageChunk(buf, kt, sc1);
    };

    const int fr  = l & 15;
    const int swz = ((l >> 4) ^ ((l >> 1) & 3)) * 8;    // ushort units
    const int aOff = (wr * 64 + fr) * 32 + swz;
    const int bOff = (wc * 64 + fr) * 32 + swz;

    f32x4 acc[4][4] = {};

    stage(0, 0);

    int cur = 0;
    for (int kt = 0; kt < KT; ++kt) {
        if (kt + 1 < KT) {
            stage(cur ^ 1, kt + 1);   // 1-deep prefetch (2 more loads)
            asm volatile("s_waitcnt vmcnt(2)" ::: "memory");   // tile kt landed
        } else {
            asm volatile("s_waitcnt vmcnt(0)" ::: "memory");
        }
        __builtin_amdgcn_s_barrier();            // raw: no auto drain
        __builtin_amdgcn_sched_barrier(0);

        const unsigned short* Ard = As + cur * 8192 + aOff;
        const unsigned short* Brd = Bs + cur * 8192 + bOff;
        short8 af[4], bf[4];
        #pragma unroll
        for (int i = 0; i < 4; ++i)
            af[i] = *reinterpret_cast<const short8*>(Ard + i * 512);
        #pragma unroll
        for (int i = 0; i < 4; ++i)
            bf[i] = *reinterpret_cast<const short8*>(Brd + i * 512);
        #pragma unroll
        for (int i = 0; i < 4; ++i)
            #pragma unroll
            for (int j = 0; j < 4; ++j)
                acc[i][j] = __builtin_amdgcn_mfma_f32_16x16x32_bf16(
                    af[i], bf[j], acc[i][j], 0, 0, 0);

        asm volatile("s_waitcnt lgkmcnt(0)" ::: "memory");  // reads done
        __builtin_amdgcn_s_barrier();            // safe to overwrite cur
        __builtin_amdgcn_sched_barrier(0);
        cur ^= 1;
    }

    // epilogue: C/D layout col = l&15, row = (l>>4)*4 + reg
    const int rq = (l >> 4) * 4;
    #pragma unroll
    for (int fn = 0; fn < 4; ++fn) {
        const int col = wc * 64 + fn * 16 + fr;
        const float bb = bias[col];
        #pragma unroll
        for (int fm = 0; fm < 4; ++fm) {
            const int rbase = m0 + wr * 64 + fm * 16 + rq;
            #pragma unroll
            for (int j = 0; j < 4; ++j) {
                const int r = rbase + j;
                if (r < M) {
                    float v = fmaxf(acc[fm][fn][j] + bb, 0.f);
                    if (WF) outf[(size_t)r * DHID + col] = v;
                    if (WB) outb[(size_t)r * DHID + col] = f2b(v);
                }
            }
        }
    }
}

extern "C" void kernel_launch(void* const* d_in, const int* in_sizes, int n_in,
                              void* d_out, int out_size, void* d_ws, size_t ws_size,
                              hipStream_t stream)
{
    const float* x   = (const float*)d_in[0];
    const int*   ei  = (const int*)d_in[1];
    const int*   src = ei;
    const int*   dst = ei + NE;
    const float* Wl0 = (const float*)d_in[2];
    const float* Wr0 = (const float*)d_in[3];
    const float* b0  = (const float*)d_in[4];
    const float* Wl1 = (const float*)d_in[5];
    const float* Wr1 = (const float*)d_in[6];
    const float* b1  = (const float*)d_in[7];
    float* out = (float*)d_out;

    // workspace layout (bytes):
    //   hist    : @0          400384
    //   offs2   : @400384     800768   (int2 per node)
    //   perm    : @1201152    2500352
    //   bsum    : @3701504    4096
    //   cursor  : @3705600    400384
    //   WT0     : @4105984    131072
    //   WT1     : @4237056    262144
    //   xb      : @4499200    25600000
    //   h0b     : @30099200   51200000
    //   aggb    : @81299200   51200000
    // total ~132.5 MB (round-0 proved >=256 MB available)
    char* ws = (char*)d_ws;
    int*            hist   = (int*)(ws);
    int2*           offs2  = (int2*)(ws + 400384);
    int*            perm   = (int*)(ws + 1201152);
    int*            bsum   = (int*)(ws + 3701504);
    int*            cursor = (int*)(ws + 3705600);
    unsigned short* WT0    = (unsigned short*)(ws + 4105984);
    unsigned short* WT1    = (unsigned short*)(ws + 4237056);
    unsigned short* xb     = (unsigned short*)(ws + 4499200);
    unsigned short* h0b    = (unsigned short*)(ws + 30099200);
    unsigned short* aggb   = (unsigned short*)(ws + 81299200);

    // prep (also zeroes hist), then CSR chain (scan fused into scatter_offs)
    prep_all_kernel<<<CONV_BLKS + 256 + 512 + NB, 256, 0, stream>>>(
        x, xb, Wl0, Wr0, WT0, Wl1, Wr1, WT1, hist);
    hist_kernel<<<(NE + 255) / 256, 256, 0, stream>>>(dst, hist);
    chunk_sum_kernel<<<NB, 256, 0, stream>>>(hist, bsum);
    scatter_offs_kernel<<<NB, 256, 0, stream>>>(hist, bsum, offs2, cursor);
    perm_kernel<<<(NE + 255) / 256, 256, 0, stream>>>(src, dst, cursor, perm);

    constexpr int NWBLK = (NN * 64) / 256;     // 25000 exactly
    const int GEMM_BLKS = (NN + 255) / 256;    // 391 blocks, full N per block

    // ---- layer 0 ----
    gather_mean128_kernel<<<NWBLK, 256, 0, stream>>>(offs2, perm, xb, aggb);
    sage_mfma_gemm<DIN, false, true><<<GEMM_BLKS, 1024, 0, stream>>>(
        aggb, xb, WT0, b0, nullptr, h0b, NN);

    // ---- layer 1 ----
    gather_mean256_kernel<<<NWBLK, 256, 0, stream>>>(offs2, perm, h0b, aggb);
    sage_mfma_gemm<DHID, true, false><<<GEMM_BLKS, 1024, 0, stream>>>(
        aggb, h0b, WT1, b1, out, nullptr, NN);
}

// Round 15
// 242.962 us; speedup vs baseline: 1.1584x; 1.1584x over previous
//
#include <hip/hip_runtime.h>

// GraphSAGE 2-layer: CSR gather-mean (bf16) + bf16 MFMA fused GEMMs.
// R15: base = R12 (best measured, 266.8us). ONE change: GEMM epilogue
//      LDS-transpose -> full-line vectorized C stores (fixes 1.45-2x write
//      amplification from fragment-scattered scalar stores).

constexpr int NN   = 100000;
constexpr int NE   = 625000;
constexpr int DIN  = 128;
constexpr int DHID = 256;
constexpr int NB   = (NN + 255) / 256;          // 391 scan chunks
constexpr int CONV_BLKS = NN * DIN / 8 / 256;   // 6250 (exact)

using short8 = __attribute__((ext_vector_type(8))) short;
using f32x4  = __attribute__((ext_vector_type(4))) float;

__device__ __forceinline__ float bf2f(unsigned int u) {
    return __uint_as_float(u << 16);
}
__device__ __forceinline__ unsigned short f2b(float f) {
    unsigned int u = __float_as_uint(f);
    unsigned int r = (u + 0x7fffu + ((u >> 16) & 1u)) >> 16;   // RNE
    return (unsigned short)r;
}
__device__ __forceinline__ unsigned int pack2(float lo, float hi) {
    return (unsigned int)f2b(lo) | ((unsigned int)f2b(hi) << 16);
}
__device__ __forceinline__ void gload16(const void* g, void* lds) {
    __builtin_amdgcn_global_load_lds(
        (const __attribute__((address_space(1))) void*)g,
        (__attribute__((address_space(3))) void*)lds, 16, 0, 0);
}

// ---------------- CSR build ------------------------------------------------
__global__ __launch_bounds__(256) void hist_kernel(const int* __restrict__ dst,
                                                   int* __restrict__ hist)
{
    int t = blockIdx.x * 256 + threadIdx.x;
    if (t < NE) atomicAdd(&hist[dst[t]], 1);
}

__global__ __launch_bounds__(256) void chunk_sum_kernel(const int* __restrict__ hist,
                                                        int* __restrict__ bsum)
{
    __shared__ int s[256];
    int i = blockIdx.x * 256 + threadIdx.x;
    s[threadIdx.x] = (i < NN) ? hist[i] : 0;
    __syncthreads();
    for (int off = 128; off > 0; off >>= 1) {
        if (threadIdx.x < off) s[threadIdx.x] += s[threadIdx.x + off];
        __syncthreads();
    }
    if (threadIdx.x == 0) bsum[blockIdx.x] = s[0];
}

__global__ __launch_bounds__(512) void scan_bsum_kernel(const int* __restrict__ bsum,
                                                        int* __restrict__ bpre)
{
    __shared__ int s[512];
    int t = threadIdx.x;
    int v = (t < NB) ? bsum[t] : 0;
    s[t] = v;
    __syncthreads();
    for (int off = 1; off < 512; off <<= 1) {
        int u = (t >= off) ? s[t - off] : 0;
        __syncthreads();
        s[t] += u;
        __syncthreads();
    }
    if (t < NB) bpre[t] = s[t] - v;        // exclusive prefix
}

__global__ __launch_bounds__(256) void scatter_offs_kernel(const int* __restrict__ hist,
                                                           const int* __restrict__ bpre,
                                                           int* __restrict__ offs,
                                                           int* __restrict__ cursor)
{
    __shared__ int s[256];
    int t = threadIdx.x;
    int i = blockIdx.x * 256 + t;
    int v = (i < NN) ? hist[i] : 0;
    s[t] = v;
    __syncthreads();
    for (int off = 1; off < 256; off <<= 1) {
        int u = (t >= off) ? s[t - off] : 0;
        __syncthreads();
        s[t] += u;
        __syncthreads();
    }
    int excl = s[t] - v + bpre[blockIdx.x];
    if (i < NN) {
        offs[i]   = excl;
        cursor[i] = excl;
    }
    if (i == NN - 1) offs[NN] = NE;
}

__global__ __launch_bounds__(256) void perm_kernel(const int* __restrict__ src,
                                                   const int* __restrict__ dst,
                                                   int* __restrict__ cursor,
                                                   int* __restrict__ perm)
{
    int t = blockIdx.x * 256 + threadIdx.x;
    if (t < NE) {
        int p = atomicAdd(&cursor[dst[t]], 1);
        perm[p] = src[t];
    }
}

// ---------------- merged prep: x->bf16, WT0, WT1, zero hist ----------------
__global__ __launch_bounds__(256) void prep_all_kernel(
    const float* __restrict__ x, unsigned short* __restrict__ xb,
    const float* __restrict__ Wl0, const float* __restrict__ Wr0,
    unsigned short* __restrict__ WT0,
    const float* __restrict__ Wl1, const float* __restrict__ Wr1,
    unsigned short* __restrict__ WT1,
    int* __restrict__ hist)
{
    int b = blockIdx.x;
    if (b < CONV_BLKS) {
        int t = b * 256 + threadIdx.x;          // [0, 1.6M) exact
        float4 v0 = reinterpret_cast<const float4*>(x)[t * 2 + 0];
        float4 v1 = reinterpret_cast<const float4*>(x)[t * 2 + 1];
        uint4 o;
        o.x = pack2(v0.x, v0.y); o.y = pack2(v0.z, v0.w);
        o.z = pack2(v1.x, v1.y); o.w = pack2(v1.z, v1.w);
        reinterpret_cast<uint4*>(xb)[t] = o;
    } else if (b < CONV_BLKS + 256) {
        int t = (b - CONV_BLKS) * 256 + threadIdx.x;   // [0, 65536)
        int n = t >> 8, k = t & 255;
        float v = (k < DIN) ? Wl0[(size_t)k * DHID + n]
                            : Wr0[(size_t)(k - DIN) * DHID + n];
        WT0[t] = f2b(v);
    } else if (b < CONV_BLKS + 256 + 512) {
        int t = (b - CONV_BLKS - 256) * 256 + threadIdx.x;   // [0, 131072)
        int n = t >> 9, k = t & 511;
        float v = (k < DHID) ? Wl1[(size_t)k * DHID + n]
                             : Wr1[(size_t)(k - DHID) * DHID + n];
        WT1[t] = f2b(v);
    } else {
        int t = (b - CONV_BLKS - 256 - 512) * 256 + threadIdx.x;
        if (t < NN) hist[t] = 0;
    }
}

// ---------------- gather-mean aggregation (32-lane rows, edge pairs) -------
// R12-exact form (best measured).
template <int D>
__global__ __launch_bounds__(256) void gather_mean_kernel(
    const int* __restrict__ offs, const int* __restrict__ perm,
    const unsigned short* __restrict__ feat, unsigned short* __restrict__ agg)
{
    const int w = (blockIdx.x * 256 + threadIdx.x) >> 6;
    const int l = threadIdx.x & 63;
    const int h = l >> 5;
    const int c = l & 31;
    if (w >= NN) return;
    const int beg = offs[w], end = offs[w + 1];
    const int deg = end - beg;
    const float sc = 1.0f / (float)(deg > 1 ? deg : 1);

    if constexpr (D == 256) {
        const uint4* base = reinterpret_cast<const uint4*>(feat);  // 32/row
        float A0[8] = {}, A1[8] = {};
        for (int e0 = 0; e0 < deg; e0 += 64) {
            const int chunk = min(deg - e0, 64);
            int pv = (l < chunk) ? perm[beg + e0 + l] : 0;
            auto dopair = [&](float* A, int p) {
                int sA = __builtin_amdgcn_readlane(pv, 2 * p);
                int sB = __builtin_amdgcn_readlane(pv, 2 * p + 1);
                int e  = 2 * p + h;
                int s  = h ? sB : sA;
                float m = (e < chunk) ? 1.0f : 0.0f;
                uint4 v = base[(size_t)s * 32 + c];
                A[0] = fmaf(bf2f(v.x & 0xffffu), m, A[0]);
                A[1] = fmaf(bf2f(v.x >> 16),     m, A[1]);
                A[2] = fmaf(bf2f(v.y & 0xffffu), m, A[2]);
                A[3] = fmaf(bf2f(v.y >> 16),     m, A[3]);
                A[4] = fmaf(bf2f(v.z & 0xffffu), m, A[4]);
                A[5] = fmaf(bf2f(v.z >> 16),     m, A[5]);
                A[6] = fmaf(bf2f(v.w & 0xffffu), m, A[6]);
                A[7] = fmaf(bf2f(v.w >> 16),     m, A[7]);
            };
            const int np = (chunk + 1) >> 1;
            int p = 0;
            if (np & 1) { dopair(A1, 0); p = 1; }
            for (; p < np; p += 2) { dopair(A0, p); dopair(A1, p + 1); }
        }
        float r[8];
        #pragma unroll
        for (int j = 0; j < 8; ++j) {
            r[j] = A0[j] + A1[j];
            r[j] += __shfl_xor(r[j], 32);
            r[j] *= sc;
        }
        if (l < 32) {
            uint4 o;
            o.x = pack2(r[0], r[1]); o.y = pack2(r[2], r[3]);
            o.z = pack2(r[4], r[5]); o.w = pack2(r[6], r[7]);
            reinterpret_cast<uint4*>(agg)[(size_t)w * 32 + c] = o;
        }
    } else {   // D == 128: 32 x uint2 per row
        const uint2* base = reinterpret_cast<const uint2*>(feat);
        float A0[4] = {}, A1[4] = {};
        for (int e0 = 0; e0 < deg; e0 += 64) {
            const int chunk = min(deg - e0, 64);
            int pv = (l < chunk) ? perm[beg + e0 + l] : 0;
            auto dopair = [&](float* A, int p) {
                int sA = __builtin_amdgcn_readlane(pv, 2 * p);
                int sB = __builtin_amdgcn_readlane(pv, 2 * p + 1);
                int e  = 2 * p + h;
                int s  = h ? sB : sA;
                float m = (e < chunk) ? 1.0f : 0.0f;
                uint2 v = base[(size_t)s * 32 + c];
                A[0] = fmaf(bf2f(v.x & 0xffffu), m, A[0]);
                A[1] = fmaf(bf2f(v.x >> 16),     m, A[1]);
                A[2] = fmaf(bf2f(v.y & 0xffffu), m, A[2]);
                A[3] = fmaf(bf2f(v.y >> 16),     m, A[3]);
            };
            const int np = (chunk + 1) >> 1;
            int p = 0;
            if (np & 1) { dopair(A1, 0); p = 1; }
            for (; p < np; p += 2) { dopair(A0, p); dopair(A1, p + 1); }
        }
        float r[4];
        #pragma unroll
        for (int j = 0; j < 4; ++j) {
            r[j] = A0[j] + A1[j];
            r[j] += __shfl_xor(r[j], 32);
            r[j] *= sc;
        }
        if (l < 32) {
            uint2 o;
            o.x = pack2(r[0], r[1]); o.y = pack2(r[2], r[3]);
            reinterpret_cast<uint2*>(agg)[(size_t)w * 32 + c] = o;
        }
    }
}

// ---------------- bf16 MFMA fused SAGE GEMM (256x256, 16 waves, 2-buf) -----
// R12 K-loop (verified). NEW epilogue: per-wave LDS transpose (4KB slot,
// reusing dead staging LDS) -> coalesced full-line vector stores.
template <int KP, bool WF, bool WB>
__global__ __launch_bounds__(1024) void sage_mfma_gemm(
    const unsigned short* __restrict__ Aagg,  // [M, KP] bf16
    const unsigned short* __restrict__ Axr,   // [M, KP] bf16
    const unsigned short* __restrict__ WT,    // [256, 2KP] bf16
    const float* __restrict__ bias,
    float* __restrict__ outf,                 // used if WF
    unsigned short* __restrict__ outb,        // used if WB
    int M)
{
    __shared__ __align__(16) unsigned short LDSBUF[4 * 8192];  // 64 KB
    unsigned short* As = LDSBUF;               // 2 x [256][32]
    unsigned short* Bs = LDSBUF + 2 * 8192;    // 2 x [256][32]

    const int t   = threadIdx.x;
    const int l   = t & 63;
    const int wid = t >> 6;          // 0..15
    const int wr  = wid >> 2;        // 0..3
    const int wc  = wid & 3;         // 0..3
    const int m0  = blockIdx.x * 256;

    const int rin = l >> 2;                       // row within 16-row chunk
    const int csw = (l & 3) ^ ((l >> 3) & 3);     // swizzled source chunk

    const int sc0 = wid * 2, sc1 = sc0 + 1;

    constexpr int K2 = 2 * KP;
    constexpr int KT = K2 / 32;

    auto stageChunk = [&](int buf, int kt, int ch) {
        const int kb = kt * 32;
        if (ch < 16) {              // A chunk: rows m0+ch*16 .. +16
            const unsigned short* Asrc;
            int kk;
            if (kb < KP) { Asrc = Aagg; kk = kb; }
            else         { Asrc = Axr;  kk = kb - KP; }
            int row = m0 + ch * 16 + rin; if (row >= M) row = M - 1;
            gload16(Asrc + (size_t)row * KP + kk + csw * 8,
                    As + buf * 8192 + ch * 512);
        } else {                    // B chunk: WT rows (ch-16)*16 .. +16
            int row = (ch - 16) * 16 + rin;
            gload16(WT + (size_t)row * K2 + kb + csw * 8,
                    Bs + buf * 8192 + (ch - 16) * 512);
        }
    };
    auto stage = [&](int buf, int kt) {
        stageChunk(buf, kt, sc0);
        stageChunk(buf, kt, sc1);
    };

    const int fr  = l & 15;
    const int swz = ((l >> 4) ^ ((l >> 1) & 3)) * 8;    // ushort units
    const int aOff = (wr * 64 + fr) * 32 + swz;
    const int bOff = (wc * 64 + fr) * 32 + swz;

    f32x4 acc[4][4] = {};

    stage(0, 0);

    int cur = 0;
    for (int kt = 0; kt < KT; ++kt) {
        if (kt + 1 < KT) {
            stage(cur ^ 1, kt + 1);   // 1-deep prefetch (2 more loads)
            asm volatile("s_waitcnt vmcnt(2)" ::: "memory");   // tile kt landed
        } else {
            asm volatile("s_waitcnt vmcnt(0)" ::: "memory");
        }
        __builtin_amdgcn_s_barrier();            // raw: no auto drain
        __builtin_amdgcn_sched_barrier(0);

        const unsigned short* Ard = As + cur * 8192 + aOff;
        const unsigned short* Brd = Bs + cur * 8192 + bOff;
        short8 af[4], bf[4];
        #pragma unroll
        for (int i = 0; i < 4; ++i)
            af[i] = *reinterpret_cast<const short8*>(Ard + i * 512);
        #pragma unroll
        for (int i = 0; i < 4; ++i)
            bf[i] = *reinterpret_cast<const short8*>(Brd + i * 512);
        #pragma unroll
        for (int i = 0; i < 4; ++i)
            #pragma unroll
            for (int j = 0; j < 4; ++j)
                acc[i][j] = __builtin_amdgcn_mfma_f32_16x16x32_bf16(
                    af[i], bf[j], acc[i][j], 0, 0, 0);

        asm volatile("s_waitcnt lgkmcnt(0)" ::: "memory");  // reads done
        __builtin_amdgcn_s_barrier();            // safe to overwrite cur
        __builtin_amdgcn_sched_barrier(0);
        cur ^= 1;
    }

    // ---- epilogue: per-wave LDS transpose -> coalesced vector stores ----
    // Wave-private 4KB slot (16 rows x 64 f32). No inter-wave barrier needed
    // (K-loop's final barrier passed; each wave touches only its own slot).
    float* cslot = reinterpret_cast<float*>(LDSBUF) + wid * 1024;
    const int rq = (l >> 4) * 4;
    const float bb0 = bias[wc * 64 + 0 * 16 + fr];
    const float bb1 = bias[wc * 64 + 1 * 16 + fr];
    const float bb2 = bias[wc * 64 + 2 * 16 + fr];
    const float bb3 = bias[wc * 64 + 3 * 16 + fr];

    #pragma unroll
    for (int fm = 0; fm < 4; ++fm) {
        // write fragment (bias+relu applied) into slot: row rq+j, col fn*16+fr
        #pragma unroll
        for (int j = 0; j < 4; ++j) {
            cslot[(rq + j) * 64 + 0 * 16 + fr] = fmaxf(acc[fm][0][j] + bb0, 0.f);
            cslot[(rq + j) * 64 + 1 * 16 + fr] = fmaxf(acc[fm][1][j] + bb1, 0.f);
            cslot[(rq + j) * 64 + 2 * 16 + fr] = fmaxf(acc[fm][2][j] + bb2, 0.f);
            cslot[(rq + j) * 64 + 3 * 16 + fr] = fmaxf(acc[fm][3][j] + bb3, 0.f);
        }
        __builtin_amdgcn_sched_barrier(0);   // keep write->read ordered region
        // read back coalesced: pass p covers rows p*4+(l>>4), lane cols (l&15)*4
        #pragma unroll
        for (int p = 0; p < 4; ++p) {
            const int rr = p * 4 + (l >> 4);
            float4 v = *reinterpret_cast<const float4*>(&cslot[rr * 64 + (l & 15) * 4]);
            const int r = m0 + wr * 64 + fm * 16 + rr;
            if (r < M) {
                const size_t off = (size_t)r * DHID + wc * 64 + (l & 15) * 4;
                if (WF) {
                    *reinterpret_cast<float4*>(&outf[off]) = v;
                }
                if (WB) {
                    uint2 o;
                    o.x = pack2(v.x, v.y);
                    o.y = pack2(v.z, v.w);
                    *reinterpret_cast<uint2*>(&outb[off]) = o;
                }
            }
        }
        __builtin_amdgcn_sched_barrier(0);   // slot reused next fm: keep order
    }
}

extern "C" void kernel_launch(void* const* d_in, const int* in_sizes, int n_in,
                              void* d_out, int out_size, void* d_ws, size_t ws_size,
                              hipStream_t stream)
{
    const float* x   = (const float*)d_in[0];
    const int*   ei  = (const int*)d_in[1];
    const int*   src = ei;
    const int*   dst = ei + NE;
    const float* Wl0 = (const float*)d_in[2];
    const float* Wr0 = (const float*)d_in[3];
    const float* b0  = (const float*)d_in[4];
    const float* Wl1 = (const float*)d_in[5];
    const float* Wr1 = (const float*)d_in[6];
    const float* b1  = (const float*)d_in[7];
    float* out = (float*)d_out;

    // workspace layout (bytes):
    //   hist    : @0          400384
    //   offs    : @400384     400640
    //   perm    : @801024     2500352
    //   bsum    : @3301376    4096
    //   bpre    : @3305472    4096
    //   cursor  : @3309568    400384
    //   WT0     : @3709952    131072
    //   WT1     : @3841024    262144
    //   xb      : @4103168    25600000
    //   h0b     : @29703168   51200000
    //   aggb    : @80903168   51200000
    // total ~132.1 MB
    char* ws = (char*)d_ws;
    int*            hist   = (int*)(ws);
    int*            offs   = (int*)(ws + 400384);
    int*            perm   = (int*)(ws + 801024);
    int*            bsum   = (int*)(ws + 3301376);
    int*            bpre   = (int*)(ws + 3305472);
    int*            cursor = (int*)(ws + 3309568);
    unsigned short* WT0    = (unsigned short*)(ws + 3709952);
    unsigned short* WT1    = (unsigned short*)(ws + 3841024);
    unsigned short* xb     = (unsigned short*)(ws + 4103168);
    unsigned short* h0b    = (unsigned short*)(ws + 29703168);
    unsigned short* aggb   = (unsigned short*)(ws + 80903168);

    // prep (also zeroes hist), then CSR chain
    prep_all_kernel<<<CONV_BLKS + 256 + 512 + NB, 256, 0, stream>>>(
        x, xb, Wl0, Wr0, WT0, Wl1, Wr1, WT1, hist);
    hist_kernel<<<(NE + 255) / 256, 256, 0, stream>>>(dst, hist);
    chunk_sum_kernel<<<NB, 256, 0, stream>>>(hist, bsum);
    scan_bsum_kernel<<<1, 512, 0, stream>>>(bsum, bpre);
    scatter_offs_kernel<<<NB, 256, 0, stream>>>(hist, bpre, offs, cursor);
    perm_kernel<<<(NE + 255) / 256, 256, 0, stream>>>(src, dst, cursor, perm);

    constexpr int NWBLK = (NN * 64) / 256;     // 25000 exactly
    const int GEMM_BLKS = (NN + 255) / 256;    // 391 blocks, full N per block

    // ---- layer 0 ----
    gather_mean_kernel<DIN><<<NWBLK, 256, 0, stream>>>(offs, perm, xb, aggb);
    sage_mfma_gemm<DIN, false, true><<<GEMM_BLKS, 1024, 0, stream>>>(
        aggb, xb, WT0, b0, nullptr, h0b, NN);

    // ---- layer 1 ----
    gather_mean_kernel<DHID><<<NWBLK, 256, 0, stream>>>(offs, perm, h0b, aggb);
    sage_mfma_gemm<DHID, true, false><<<GEMM_BLKS, 1024, 0, stream>>>(
        aggb, h0b, WT1, b1, out, nullptr, NN);
}

// Round 17
// 240.757 us; speedup vs baseline: 1.1690x; 1.0092x over previous
//
#include <hip/hip_runtime.h>

// GraphSAGE 2-layer: CSR gather-mean (bf16) + bf16 MFMA fused GEMMs.
// R17: R16 intent with compile fix — nontemporal stores need clang
//      ext_vector_type pointers (f32x4/u32x2), not HIP_vector_type.

constexpr int NN   = 100000;
constexpr int NE   = 625000;
constexpr int DIN  = 128;
constexpr int DHID = 256;
constexpr int NB   = (NN + 255) / 256;          // 391 scan chunks
constexpr int CONV_BLKS = NN * DIN / 8 / 256;   // 6250 (exact)

using short8 = __attribute__((ext_vector_type(8))) short;
using f32x4  = __attribute__((ext_vector_type(4))) float;
using u32x2  = __attribute__((ext_vector_type(2))) unsigned int;

__device__ __forceinline__ float bf2f(unsigned int u) {
    return __uint_as_float(u << 16);
}
__device__ __forceinline__ unsigned short f2b(float f) {
    unsigned int u = __float_as_uint(f);
    unsigned int r = (u + 0x7fffu + ((u >> 16) & 1u)) >> 16;   // RNE
    return (unsigned short)r;
}
__device__ __forceinline__ unsigned int pack2(float lo, float hi) {
    return (unsigned int)f2b(lo) | ((unsigned int)f2b(hi) << 16);
}
__device__ __forceinline__ void gload16(const void* g, void* lds) {
    __builtin_amdgcn_global_load_lds(
        (const __attribute__((address_space(1))) void*)g,
        (__attribute__((address_space(3))) void*)lds, 16, 0, 0);
}

// ---------------- CSR build ------------------------------------------------
__global__ __launch_bounds__(256) void hist_kernel(const int* __restrict__ dst,
                                                   int* __restrict__ hist)
{
    int t = blockIdx.x * 256 + threadIdx.x;
    if (t < NE) atomicAdd(&hist[dst[t]], 1);
}

__global__ __launch_bounds__(256) void chunk_sum_kernel(const int* __restrict__ hist,
                                                        int* __restrict__ bsum)
{
    __shared__ int s[256];
    int i = blockIdx.x * 256 + threadIdx.x;
    s[threadIdx.x] = (i < NN) ? hist[i] : 0;
    __syncthreads();
    for (int off = 128; off > 0; off >>= 1) {
        if (threadIdx.x < off) s[threadIdx.x] += s[threadIdx.x + off];
        __syncthreads();
    }
    if (threadIdx.x == 0) bsum[blockIdx.x] = s[0];
}

__global__ __launch_bounds__(512) void scan_bsum_kernel(const int* __restrict__ bsum,
                                                        int* __restrict__ bpre)
{
    __shared__ int s[512];
    int t = threadIdx.x;
    int v = (t < NB) ? bsum[t] : 0;
    s[t] = v;
    __syncthreads();
    for (int off = 1; off < 512; off <<= 1) {
        int u = (t >= off) ? s[t - off] : 0;
        __syncthreads();
        s[t] += u;
        __syncthreads();
    }
    if (t < NB) bpre[t] = s[t] - v;        // exclusive prefix
}

__global__ __launch_bounds__(256) void scatter_offs_kernel(const int* __restrict__ hist,
                                                           const int* __restrict__ bpre,
                                                           int* __restrict__ offs,
                                                           int* __restrict__ cursor)
{
    __shared__ int s[256];
    int t = threadIdx.x;
    int i = blockIdx.x * 256 + t;
    int v = (i < NN) ? hist[i] : 0;
    s[t] = v;
    __syncthreads();
    for (int off = 1; off < 256; off <<= 1) {
        int u = (t >= off) ? s[t - off] : 0;
        __syncthreads();
        s[t] += u;
        __syncthreads();
    }
    int excl = s[t] - v + bpre[blockIdx.x];
    if (i < NN) {
        offs[i]   = excl;
        cursor[i] = excl;
    }
    if (i == NN - 1) offs[NN] = NE;
}

__global__ __launch_bounds__(256) void perm_kernel(const int* __restrict__ src,
                                                   const int* __restrict__ dst,
                                                   int* __restrict__ cursor,
                                                   int* __restrict__ perm)
{
    int t = blockIdx.x * 256 + threadIdx.x;
    if (t < NE) {
        int p = atomicAdd(&cursor[dst[t]], 1);
        perm[p] = src[t];
    }
}

// ---------------- merged prep: x->bf16, WT0, WT1, zero hist ----------------
__global__ __launch_bounds__(256) void prep_all_kernel(
    const float* __restrict__ x, unsigned short* __restrict__ xb,
    const float* __restrict__ Wl0, const float* __restrict__ Wr0,
    unsigned short* __restrict__ WT0,
    const float* __restrict__ Wl1, const float* __restrict__ Wr1,
    unsigned short* __restrict__ WT1,
    int* __restrict__ hist)
{
    int b = blockIdx.x;
    if (b < CONV_BLKS) {
        int t = b * 256 + threadIdx.x;          // [0, 1.6M) exact
        float4 v0 = reinterpret_cast<const float4*>(x)[t * 2 + 0];
        float4 v1 = reinterpret_cast<const float4*>(x)[t * 2 + 1];
        uint4 o;
        o.x = pack2(v0.x, v0.y); o.y = pack2(v0.z, v0.w);
        o.z = pack2(v1.x, v1.y); o.w = pack2(v1.z, v1.w);
        reinterpret_cast<uint4*>(xb)[t] = o;
    } else if (b < CONV_BLKS + 256) {
        int t = (b - CONV_BLKS) * 256 + threadIdx.x;   // [0, 65536)
        int n = t >> 8, k = t & 255;
        float v = (k < DIN) ? Wl0[(size_t)k * DHID + n]
                            : Wr0[(size_t)(k - DIN) * DHID + n];
        WT0[t] = f2b(v);
    } else if (b < CONV_BLKS + 256 + 512) {
        int t = (b - CONV_BLKS - 256) * 256 + threadIdx.x;   // [0, 131072)
        int n = t >> 9, k = t & 511;
        float v = (k < DHID) ? Wl1[(size_t)k * DHID + n]
                             : Wr1[(size_t)(k - DHID) * DHID + n];
        WT1[t] = f2b(v);
    } else {
        int t = (b - CONV_BLKS - 256 - 512) * 256 + threadIdx.x;
        if (t < NN) hist[t] = 0;
    }
}

// ---------------- gather-mean aggregation (32-lane rows, edge pairs) -------
// R12-exact form (best measured).
template <int D>
__global__ __launch_bounds__(256) void gather_mean_kernel(
    const int* __restrict__ offs, const int* __restrict__ perm,
    const unsigned short* __restrict__ feat, unsigned short* __restrict__ agg)
{
    const int w = (blockIdx.x * 256 + threadIdx.x) >> 6;
    const int l = threadIdx.x & 63;
    const int h = l >> 5;
    const int c = l & 31;
    if (w >= NN) return;
    const int beg = offs[w], end = offs[w + 1];
    const int deg = end - beg;
    const float sc = 1.0f / (float)(deg > 1 ? deg : 1);

    if constexpr (D == 256) {
        const uint4* base = reinterpret_cast<const uint4*>(feat);  // 32/row
        float A0[8] = {}, A1[8] = {};
        for (int e0 = 0; e0 < deg; e0 += 64) {
            const int chunk = min(deg - e0, 64);
            int pv = (l < chunk) ? perm[beg + e0 + l] : 0;
            auto dopair = [&](float* A, int p) {
                int sA = __builtin_amdgcn_readlane(pv, 2 * p);
                int sB = __builtin_amdgcn_readlane(pv, 2 * p + 1);
                int e  = 2 * p + h;
                int s  = h ? sB : sA;
                float m = (e < chunk) ? 1.0f : 0.0f;
                uint4 v = base[(size_t)s * 32 + c];
                A[0] = fmaf(bf2f(v.x & 0xffffu), m, A[0]);
                A[1] = fmaf(bf2f(v.x >> 16),     m, A[1]);
                A[2] = fmaf(bf2f(v.y & 0xffffu), m, A[2]);
                A[3] = fmaf(bf2f(v.y >> 16),     m, A[3]);
                A[4] = fmaf(bf2f(v.z & 0xffffu), m, A[4]);
                A[5] = fmaf(bf2f(v.z >> 16),     m, A[5]);
                A[6] = fmaf(bf2f(v.w & 0xffffu), m, A[6]);
                A[7] = fmaf(bf2f(v.w >> 16),     m, A[7]);
            };
            const int np = (chunk + 1) >> 1;
            int p = 0;
            if (np & 1) { dopair(A1, 0); p = 1; }
            for (; p < np; p += 2) { dopair(A0, p); dopair(A1, p + 1); }
        }
        float r[8];
        #pragma unroll
        for (int j = 0; j < 8; ++j) {
            r[j] = A0[j] + A1[j];
            r[j] += __shfl_xor(r[j], 32);
            r[j] *= sc;
        }
        if (l < 32) {
            uint4 o;
            o.x = pack2(r[0], r[1]); o.y = pack2(r[2], r[3]);
            o.z = pack2(r[4], r[5]); o.w = pack2(r[6], r[7]);
            reinterpret_cast<uint4*>(agg)[(size_t)w * 32 + c] = o;
        }
    } else {   // D == 128: 32 x uint2 per row
        const uint2* base = reinterpret_cast<const uint2*>(feat);
        float A0[4] = {}, A1[4] = {};
        for (int e0 = 0; e0 < deg; e0 += 64) {
            const int chunk = min(deg - e0, 64);
            int pv = (l < chunk) ? perm[beg + e0 + l] : 0;
            auto dopair = [&](float* A, int p) {
                int sA = __builtin_amdgcn_readlane(pv, 2 * p);
                int sB = __builtin_amdgcn_readlane(pv, 2 * p + 1);
                int e  = 2 * p + h;
                int s  = h ? sB : sA;
                float m = (e < chunk) ? 1.0f : 0.0f;
                uint2 v = base[(size_t)s * 32 + c];
                A[0] = fmaf(bf2f(v.x & 0xffffu), m, A[0]);
                A[1] = fmaf(bf2f(v.x >> 16),     m, A[1]);
                A[2] = fmaf(bf2f(v.y & 0xffffu), m, A[2]);
                A[3] = fmaf(bf2f(v.y >> 16),     m, A[3]);
            };
            const int np = (chunk + 1) >> 1;
            int p = 0;
            if (np & 1) { dopair(A1, 0); p = 1; }
            for (; p < np; p += 2) { dopair(A0, p); dopair(A1, p + 1); }
        }
        float r[4];
        #pragma unroll
        for (int j = 0; j < 4; ++j) {
            r[j] = A0[j] + A1[j];
            r[j] += __shfl_xor(r[j], 32);
            r[j] *= sc;
        }
        if (l < 32) {
            uint2 o;
            o.x = pack2(r[0], r[1]); o.y = pack2(r[2], r[3]);
            reinterpret_cast<uint2*>(agg)[(size_t)w * 32 + c] = o;
        }
    }
}

// ---------------- bf16 MFMA fused SAGE GEMM (256x256, 16 waves, 2-buf) -----
// R15 K-loop + LDS-transpose epilogue. R17: nontemporal output stores
// via ext_vector_type pointers.
template <int KP, bool WF, bool WB>
__global__ __launch_bounds__(1024) void sage_mfma_gemm(
    const unsigned short* __restrict__ Aagg,  // [M, KP] bf16
    const unsigned short* __restrict__ Axr,   // [M, KP] bf16
    const unsigned short* __restrict__ WT,    // [256, 2KP] bf16
    const float* __restrict__ bias,
    float* __restrict__ outf,                 // used if WF
    unsigned short* __restrict__ outb,        // used if WB
    int M)
{
    __shared__ __align__(16) unsigned short LDSBUF[4 * 8192];  // 64 KB
    unsigned short* As = LDSBUF;               // 2 x [256][32]
    unsigned short* Bs = LDSBUF + 2 * 8192;    // 2 x [256][32]

    const int t   = threadIdx.x;
    const int l   = t & 63;
    const int wid = t >> 6;          // 0..15
    const int wr  = wid >> 2;        // 0..3
    const int wc  = wid & 3;         // 0..3
    const int m0  = blockIdx.x * 256;

    const int rin = l >> 2;                       // row within 16-row chunk
    const int csw = (l & 3) ^ ((l >> 3) & 3);     // swizzled source chunk

    const int sc0 = wid * 2, sc1 = sc0 + 1;

    constexpr int K2 = 2 * KP;
    constexpr int KT = K2 / 32;

    auto stageChunk = [&](int buf, int kt, int ch) {
        const int kb = kt * 32;
        if (ch < 16) {              // A chunk: rows m0+ch*16 .. +16
            const unsigned short* Asrc;
            int kk;
            if (kb < KP) { Asrc = Aagg; kk = kb; }
            else         { Asrc = Axr;  kk = kb - KP; }
            int row = m0 + ch * 16 + rin; if (row >= M) row = M - 1;
            gload16(Asrc + (size_t)row * KP + kk + csw * 8,
                    As + buf * 8192 + ch * 512);
        } else {                    // B chunk: WT rows (ch-16)*16 .. +16
            int row = (ch - 16) * 16 + rin;
            gload16(WT + (size_t)row * K2 + kb + csw * 8,
                    Bs + buf * 8192 + (ch - 16) * 512);
        }
    };
    auto stage = [&](int buf, int kt) {
        stageChunk(buf, kt, sc0);
        stageChunk(buf, kt, sc1);
    };

    const int fr  = l & 15;
    const int swz = ((l >> 4) ^ ((l >> 1) & 3)) * 8;    // ushort units
    const int aOff = (wr * 64 + fr) * 32 + swz;
    const int bOff = (wc * 64 + fr) * 32 + swz;

    f32x4 acc[4][4] = {};

    stage(0, 0);

    int cur = 0;
    for (int kt = 0; kt < KT; ++kt) {
        if (kt + 1 < KT) {
            stage(cur ^ 1, kt + 1);   // 1-deep prefetch (2 more loads)
            asm volatile("s_waitcnt vmcnt(2)" ::: "memory");   // tile kt landed
        } else {
            asm volatile("s_waitcnt vmcnt(0)" ::: "memory");
        }
        __builtin_amdgcn_s_barrier();            // raw: no auto drain
        __builtin_amdgcn_sched_barrier(0);

        const unsigned short* Ard = As + cur * 8192 + aOff;
        const unsigned short* Brd = Bs + cur * 8192 + bOff;
        short8 af[4], bf[4];
        #pragma unroll
        for (int i = 0; i < 4; ++i)
            af[i] = *reinterpret_cast<const short8*>(Ard + i * 512);
        #pragma unroll
        for (int i = 0; i < 4; ++i)
            bf[i] = *reinterpret_cast<const short8*>(Brd + i * 512);
        #pragma unroll
        for (int i = 0; i < 4; ++i)
            #pragma unroll
            for (int j = 0; j < 4; ++j)
                acc[i][j] = __builtin_amdgcn_mfma_f32_16x16x32_bf16(
                    af[i], bf[j], acc[i][j], 0, 0, 0);

        asm volatile("s_waitcnt lgkmcnt(0)" ::: "memory");  // reads done
        __builtin_amdgcn_s_barrier();            // safe to overwrite cur
        __builtin_amdgcn_sched_barrier(0);
        cur ^= 1;
    }

    // ---- epilogue: per-wave LDS transpose -> coalesced NT vector stores ----
    float* cslot = reinterpret_cast<float*>(LDSBUF) + wid * 1024;
    const int rq = (l >> 4) * 4;
    const float bb0 = bias[wc * 64 + 0 * 16 + fr];
    const float bb1 = bias[wc * 64 + 1 * 16 + fr];
    const float bb2 = bias[wc * 64 + 2 * 16 + fr];
    const float bb3 = bias[wc * 64 + 3 * 16 + fr];

    #pragma unroll
    for (int fm = 0; fm < 4; ++fm) {
        #pragma unroll
        for (int j = 0; j < 4; ++j) {
            cslot[(rq + j) * 64 + 0 * 16 + fr] = fmaxf(acc[fm][0][j] + bb0, 0.f);
            cslot[(rq + j) * 64 + 1 * 16 + fr] = fmaxf(acc[fm][1][j] + bb1, 0.f);
            cslot[(rq + j) * 64 + 2 * 16 + fr] = fmaxf(acc[fm][2][j] + bb2, 0.f);
            cslot[(rq + j) * 64 + 3 * 16 + fr] = fmaxf(acc[fm][3][j] + bb3, 0.f);
        }
        __builtin_amdgcn_sched_barrier(0);   // keep write->read ordered region
        #pragma unroll
        for (int p = 0; p < 4; ++p) {
            const int rr = p * 4 + (l >> 4);
            f32x4 v = *reinterpret_cast<const f32x4*>(&cslot[rr * 64 + (l & 15) * 4]);
            const int r = m0 + wr * 64 + fm * 16 + rr;
            if (r < M) {
                const size_t off = (size_t)r * DHID + wc * 64 + (l & 15) * 4;
                if (WF) {
                    __builtin_nontemporal_store(v,
                        reinterpret_cast<f32x4*>(&outf[off]));
                }
                if (WB) {
                    u32x2 o;
                    o.x = pack2(v.x, v.y);
                    o.y = pack2(v.z, v.w);
                    __builtin_nontemporal_store(o,
                        reinterpret_cast<u32x2*>(&outb[off]));
                }
            }
        }
        __builtin_amdgcn_sched_barrier(0);   // slot reused next fm: keep order
    }
}

extern "C" void kernel_launch(void* const* d_in, const int* in_sizes, int n_in,
                              void* d_out, int out_size, void* d_ws, size_t ws_size,
                              hipStream_t stream)
{
    const float* x   = (const float*)d_in[0];
    const int*   ei  = (const int*)d_in[1];
    const int*   src = ei;
    const int*   dst = ei + NE;
    const float* Wl0 = (const float*)d_in[2];
    const float* Wr0 = (const float*)d_in[3];
    const float* b0  = (const float*)d_in[4];
    const float* Wl1 = (const float*)d_in[5];
    const float* Wr1 = (const float*)d_in[6];
    const float* b1  = (const float*)d_in[7];
    float* out = (float*)d_out;

    // workspace layout (bytes):
    //   hist    : @0          400384
    //   offs    : @400384     400640
    //   perm    : @801024     2500352
    //   bsum    : @3301376    4096
    //   bpre    : @3305472    4096
    //   cursor  : @3309568    400384
    //   WT0     : @3709952    131072
    //   WT1     : @3841024    262144
    //   xb      : @4103168    25600000
    //   h0b     : @29703168   51200000
    //   aggb    : @80903168   51200000
    // total ~132.1 MB
    char* ws = (char*)d_ws;
    int*            hist   = (int*)(ws);
    int*            offs   = (int*)(ws + 400384);
    int*            perm   = (int*)(ws + 801024);
    int*            bsum   = (int*)(ws + 3301376);
    int*            bpre   = (int*)(ws + 3305472);
    int*            cursor = (int*)(ws + 3309568);
    unsigned short* WT0    = (unsigned short*)(ws + 3709952);
    unsigned short* WT1    = (unsigned short*)(ws + 3841024);
    unsigned short* xb     = (unsigned short*)(ws + 4103168);
    unsigned short* h0b    = (unsigned short*)(ws + 29703168);
    unsigned short* aggb   = (unsigned short*)(ws + 80903168);

    // prep (also zeroes hist), then CSR chain
    prep_all_kernel<<<CONV_BLKS + 256 + 512 + NB, 256, 0, stream>>>(
        x, xb, Wl0, Wr0, WT0, Wl1, Wr1, WT1, hist);
    hist_kernel<<<(NE + 255) / 256, 256, 0, stream>>>(dst, hist);
    chunk_sum_kernel<<<NB, 256, 0, stream>>>(hist, bsum);
    scan_bsum_kernel<<<1, 512, 0, stream>>>(bsum, bpre);
    scatter_offs_kernel<<<NB, 256, 0, stream>>>(hist, bpre, offs, cursor);
    perm_kernel<<<(NE + 255) / 256, 256, 0, stream>>>(src, dst, cursor, perm);

    constexpr int NWBLK = (NN * 64) / 256;     // 25000 exactly
    const int GEMM_BLKS = (NN + 255) / 256;    // 391 blocks, full N per block

    // ---- layer 0 ----
    gather_mean_kernel<DIN><<<NWBLK, 256, 0, stream>>>(offs, perm, xb, aggb);
    sage_mfma_gemm<DIN, false, true><<<GEMM_BLKS, 1024, 0, stream>>>(
        aggb, xb, WT0, b0, nullptr, h0b, NN);

    // ---- layer 1 ----
    gather_mean_kernel<DHID><<<NWBLK, 256, 0, stream>>>(offs, perm, h0b, aggb);
    sage_mfma_gemm<DHID, true, false><<<GEMM_BLKS, 1024, 0, stream>>>(
        aggb, h0b, WT1, b1, out, nullptr, NN);
}